// Round 5
// baseline (59.395 us; speedup 1.0000x reference)
//
#include <hip/hip_runtime.h>

// Problem constants (fixed-shape bench)
#define BB 2
#define HH 8
#define LL 32
#define CHK 64
#define DD 64
#define MAX_REL 32
#define NN 2048            // LL*CHK
#define NROWS (BB * HH * NN)   // 32768
#define RPB 16             // rows per block (score kernel)

typedef float f32x4 __attribute__((ext_vector_type(4)));

// ---------- Kernel 1: scores[row][k] = x[row,:] . emb[b,q,k,:] -> ws ----------
__global__ __launch_bounds__(256) void score_kernel(
    const float* __restrict__ x,      // [B,H,N,D]
    const int*   __restrict__ pos,    // [B,L,L]
    const float* __restrict__ table,  // [2*MAX_REL+1, D]
    float*       __restrict__ sc)     // [NROWS, 32]
{
    const int blk = blockIdx.x;        // 0..2047
    const int sub = blk & 3;
    const int q   = (blk >> 2) & (LL - 1);
    const int bh  = blk >> 7;
    const int b   = bh >> 3;

    const int t    = threadIdx.x;
    const int k    = t >> 3;           // 0..31
    const int part = t & 7;            // 0..7

    int p = pos[(b * LL + q) * LL + k];
    p = min(max(p, -MAX_REL), MAX_REL) + MAX_REL;
    const float* erow = table + (size_t)p * DD + part * 8;
    const f32x4 ea = *(const f32x4*)(erow);
    const f32x4 eb = *(const f32x4*)(erow + 4);

    const int row0 = (bh << 11) + (q << 6) + (sub << 4);
    const float* xbase = x + (size_t)row0 * DD + part * 8;

    #pragma unroll 4
    for (int r = 0; r < RPB; ++r) {
        const f32x4 xa = *(const f32x4*)(xbase + (size_t)r * DD);
        const f32x4 xb = *(const f32x4*)(xbase + (size_t)r * DD + 4);
        float s = xa.x * ea.x + xa.y * ea.y + xa.z * ea.z + xa.w * ea.w
                + xb.x * eb.x + xb.y * eb.y + xb.z * eb.z + xb.w * eb.w;
        s += __shfl_xor(s, 1);
        s += __shfl_xor(s, 2);
        s += __shfl_xor(s, 4);
        if (part == 0) sc[(size_t)(row0 + r) * 32 + k] = s;
    }
}

// ---------- Kernel 2: fill-like broadcast store (no shfl/LDS/barrier) ----------
__global__ __launch_bounds__(256) void bcast_kernel(
    const float* __restrict__ sc,     // [NROWS, 32] (L2-resident)
    float*       __restrict__ out)    // [B,H,N,N]
{
    const int wid  = blockIdx.x * 4 + (threadIdx.x >> 6);  // 0..16383
    const int lane = threadIdx.x & 63;
    const int g    = lane >> 4;        // 0..3: which score within a 4-group

    #pragma unroll
    for (int i = 0; i < 2; ++i) {
        const int row = wid * 2 + i;
        const float* srow = sc + (size_t)row * 32;
        float v[8];
        #pragma unroll
        for (int j = 0; j < 8; ++j)
            v[j] = srow[4 * j + g];    // 16-lane broadcast loads, L2-hit

        f32x4* orow = (f32x4*)(out + (size_t)row * NN);
        #pragma unroll
        for (int j = 0; j < 8; ++j) {
            f32x4 v4 = {v[j], v[j], v[j], v[j]};
            orow[j * 64 + lane] = v4;  // 8 back-to-back coalesced 1KB stores
        }
    }
}

// ---------- Fallback: R1 single-kernel (used only if ws_size < 4 MB) ----------
__global__ __launch_bounds__(256) void relpos_fused(
    const float* __restrict__ x, const int* __restrict__ pos,
    const float* __restrict__ table, float* __restrict__ out)
{
    const int blk = blockIdx.x;
    const int sub = blk & 3;
    const int q   = (blk >> 2) & (LL - 1);
    const int bh  = blk >> 7;
    const int b   = bh >> 3;
    const int t    = threadIdx.x;
    const int k    = t >> 3;
    const int part = t & 7;

    int p = pos[(b * LL + q) * LL + k];
    p = min(max(p, -MAX_REL), MAX_REL) + MAX_REL;
    const float* erow = table + (size_t)p * DD + part * 8;
    const f32x4 ea = *(const f32x4*)(erow);
    const f32x4 eb = *(const f32x4*)(erow + 4);

    __shared__ float sk[RPB][32];
    const int row0 = (bh << 11) + (q << 6) + (sub << 4);
    const float* xbase = x + (size_t)row0 * DD + part * 8;

    #pragma unroll 4
    for (int r = 0; r < RPB; ++r) {
        const f32x4 xa = *(const f32x4*)(xbase + (size_t)r * DD);
        const f32x4 xb = *(const f32x4*)(xbase + (size_t)r * DD + 4);
        float s = xa.x * ea.x + xa.y * ea.y + xa.z * ea.z + xa.w * ea.w
                + xb.x * eb.x + xb.y * eb.y + xb.z * eb.z + xb.w * eb.w;
        s += __shfl_xor(s, 1);
        s += __shfl_xor(s, 2);
        s += __shfl_xor(s, 4);
        if (part == 0) sk[r][k] = s;
    }
    __syncthreads();

    const int k0 = t >> 4;
    f32x4* obase = (f32x4*)(out + (size_t)row0 * NN);
    #pragma unroll
    for (int r = 0; r < RPB; ++r) {
        const float v0 = sk[r][k0];
        const float v1 = sk[r][16 + k0];
        f32x4* orow = obase + (size_t)r * (NN / 4);
        orow[t]       = (f32x4){v0, v0, v0, v0};
        orow[t + 256] = (f32x4){v1, v1, v1, v1};
    }
}

extern "C" void kernel_launch(void* const* d_in, const int* in_sizes, int n_in,
                              void* d_out, int out_size, void* d_ws, size_t ws_size,
                              hipStream_t stream) {
    const float* x     = (const float*)d_in[0];
    const int*   pos   = (const int*)d_in[1];
    const float* table = (const float*)d_in[2];
    float*       out   = (float*)d_out;

    if (ws_size >= (size_t)NROWS * 32 * sizeof(float)) {
        float* sc = (float*)d_ws;
        score_kernel<<<dim3(NROWS / RPB), 256, 0, stream>>>(x, pos, table, sc);
        bcast_kernel<<<dim3(NROWS / 2 / 4), 256, 0, stream>>>(sc, out);
    } else {
        relpos_fused<<<dim3(NROWS / RPB), 256, 0, stream>>>(x, pos, table, out);
    }
}

// Round 6
// 54.475 us; speedup vs baseline: 1.0903x; 1.0903x over previous
//
#include <hip/hip_runtime.h>

// Problem constants (fixed-shape bench)
#define BB 2
#define HH 8
#define LL 32
#define CHK 64
#define DD 64
#define MAX_REL 32
#define NN 2048            // LL*CHK
#define RPB 16             // rows per block

typedef float f32x4 __attribute__((ext_vector_type(4)));

// Best variant (R1): one block (256 threads) per 16 consecutive output rows,
// all within one (b,h,q) chunk-row. Embedding fragments live in registers
// across all rows. Phase 1: 16 rounds of dot products -> sk[r][k] in LDS.
// Phase 2: stream 16 rows x 8 KB = 128 KB of broadcast output, coalesced.
//
// Measured 54.4 us; two-point fit vs the vendor 1-GiB fill kernel puts this
// exactly on the hardware's size-scaling line (steady ~8 TB/s + ~20 us
// launch/ramp/tail) -> write-bandwidth roofline for a 268 MB dispatch.
__global__ __launch_bounds__(256) void relpos_kernel(
    const float* __restrict__ x,      // [B,H,N,D]
    const int*   __restrict__ pos,    // [B,L,L]
    const float* __restrict__ table,  // [2*MAX_REL+1, D]
    float*       __restrict__ out)    // [B,H,N,N]
{
    const int blk = blockIdx.x;        // 0 .. B*H*L*4 - 1  (2048)
    const int sub = blk & 3;           // 16-row group within the 64-row chunk
    const int q   = (blk >> 2) & (LL - 1);
    const int bh  = blk >> 7;          // b*H + h
    const int b   = bh >> 3;

    const int t    = threadIdx.x;
    const int k    = t >> 3;           // 0..31  column block
    const int part = t & 7;            // 0..7   8-float slice of D

    // Gather embedding row for (b,q,k) once; keep 8 floats in registers.
    int p = pos[(b * LL + q) * LL + k];
    p = min(max(p, -MAX_REL), MAX_REL) + MAX_REL;
    const float* erow = table + (size_t)p * DD + part * 8;
    const f32x4 ea = *(const f32x4*)(erow);
    const f32x4 eb = *(const f32x4*)(erow + 4);

    __shared__ float sk[RPB][32];

    const int row0 = (bh << 11) + (q << 6) + (sub << 4); // first global row
    const float* xbase = x + (size_t)row0 * DD + part * 8;

    #pragma unroll 4
    for (int r = 0; r < RPB; ++r) {
        const f32x4 xa = *(const f32x4*)(xbase + (size_t)r * DD);
        const f32x4 xb = *(const f32x4*)(xbase + (size_t)r * DD + 4);
        float s = xa.x * ea.x + xa.y * ea.y + xa.z * ea.z + xa.w * ea.w
                + xb.x * eb.x + xb.y * eb.y + xb.z * eb.z + xb.w * eb.w;
        s += __shfl_xor(s, 1);
        s += __shfl_xor(s, 2);
        s += __shfl_xor(s, 4);
        if (part == 0) sk[r][k] = s;
    }
    __syncthreads();

    // Phase 2: each thread stores float4 columns t and t+256 of every row.
    const int k0 = t >> 4;                    // 16 float4 per 64-float block
    f32x4* obase = (f32x4*)(out + (size_t)row0 * NN);
    #pragma unroll
    for (int r = 0; r < RPB; ++r) {
        const float v0 = sk[r][k0];
        const float v1 = sk[r][16 + k0];
        f32x4* orow = obase + (size_t)r * (NN / 4);
        orow[t]       = (f32x4){v0, v0, v0, v0};
        orow[t + 256] = (f32x4){v1, v1, v1, v1};
    }
}

extern "C" void kernel_launch(void* const* d_in, const int* in_sizes, int n_in,
                              void* d_out, int out_size, void* d_ws, size_t ws_size,
                              hipStream_t stream) {
    const float* x     = (const float*)d_in[0];
    const int*   pos   = (const int*)d_in[1];
    const float* table = (const float*)d_in[2];
    float*       out   = (float*)d_out;

    dim3 grid(BB * HH * LL * (CHK / RPB));   // 2048 blocks
    relpos_kernel<<<grid, 256, 0, stream>>>(x, pos, table, out);
}